// Round 4
// baseline (1602.834 us; speedup 1.0000x reference)
//
#include <hip/hip_runtime.h>
#include <hip/hip_bf16.h>
#include <cstdint>

#define B_ 256
#define D_ 128
#define T_ 512
#define H_ 256
#define C_ 10

using f32x4 = __attribute__((ext_vector_type(4))) float;
using s16x8 = __attribute__((ext_vector_type(8))) short;

__device__ __forceinline__ unsigned short f2bf(float f) {
    union { float f; uint32_t u; } a; a.f = f;
    uint32_t u = a.u;
    uint32_t r = (u + 0x7fffu + ((u >> 16) & 1u)) >> 16;   // RNE
    return (unsigned short)r;
}

__device__ __forceinline__ float sigm(float v) { return 1.0f / (1.0f + __expf(-v)); }

__device__ __forceinline__ s16x8 as_frag(uint4 v) {
    union { uint4 u; s16x8 s; } c; c.u = v; return c.s;
}

// lgkm-only barrier: orders LDS without draining in-flight global ops.
__device__ __forceinline__ void bar_lds() {
    asm volatile("s_waitcnt lgkmcnt(0)\n\ts_barrier" ::: "memory");
}

// ---------------------------------------------------------------------------
// Kernel 1: x [B][D][T] f32 -> xt in MFMA-A-fragment order (bf16 pairs, u32):
//   idx32(t,bc,kk,lane,e) = (((t*16+bc)*4+kk)*64 + lane)*4 + e
// where lane=(b&15)+16*quad, d = kk*32+quad*8+e*2(+1).
// Block = (bc, 16-t tile); grid 16*32=512.
// ---------------------------------------------------------------------------
__global__ void xt_kernel(const float* __restrict__ x, uint32_t* __restrict__ xtf) {
    __shared__ unsigned short tile[16][128][17];   // [b_l][d][tl]
    const int bc = blockIdx.x >> 5;
    const int t0 = (blockIdx.x & 31) << 4;
    const int tid = threadIdx.x;

#pragma unroll
    for (int i = 0; i < 8; ++i) {
        int idx = i * 256 + tid;
        int b_l = idx >> 7, d = idx & 127;
        const float* src = x + ((size_t)(bc * 16 + b_l) * D_ + d) * T_ + t0;
        float4 f0 = *(const float4*)(src);
        float4 f1 = *(const float4*)(src + 4);
        float4 f2 = *(const float4*)(src + 8);
        float4 f3 = *(const float4*)(src + 12);
        unsigned short* dst = &tile[b_l][d][0];
        dst[0]=f2bf(f0.x); dst[1]=f2bf(f0.y); dst[2]=f2bf(f0.z); dst[3]=f2bf(f0.w);
        dst[4]=f2bf(f1.x); dst[5]=f2bf(f1.y); dst[6]=f2bf(f1.z); dst[7]=f2bf(f1.w);
        dst[8]=f2bf(f2.x); dst[9]=f2bf(f2.y); dst[10]=f2bf(f2.z); dst[11]=f2bf(f2.w);
        dst[12]=f2bf(f3.x); dst[13]=f2bf(f3.y); dst[14]=f2bf(f3.z); dst[15]=f2bf(f3.w);
    }
    __syncthreads();

    // thread covers 64 consecutive u32 of output: tl=tid>>4, kk=(tid>>2)&3,
    // lane = (tid&3)*16 + (q>>2), e = q&3  (q=0..63)
    const int tl = tid >> 4;
    const int kk = (tid >> 2) & 3;
    const int lq = tid & 3;             // quad
    uint32_t vals[64];
#pragma unroll
    for (int q = 0; q < 64; ++q) {
        int brow = q >> 2;              // lane&15
        int e = q & 3;
        int d = kk * 32 + lq * 8 + e * 2;
        uint32_t lo = tile[brow][d][tl];
        uint32_t hi = tile[brow][d + 1][tl];
        vals[q] = lo | (hi << 16);
    }
    size_t S = ((((size_t)(t0 + tl) * 16 + bc) * 4 + kk) * 64 + (size_t)lq * 16) * 4;
#pragma unroll
    for (int q = 0; q < 16; ++q)
        *(uint4*)(xtf + S + q * 4) = *(uint4*)&vals[q * 4];
}

// ---------------------------------------------------------------------------
// Kernel 2: persistent LSTM recurrence + fused output projection.
// 256 blocks = 16 bc x 16 hc, 256 threads (4 waves, wave = gate).
// Protocol per step: producer stores 128 tagged u64 ([t | 2 bf16]) into a
// contiguous per-producer 1KB region, then a relaxed flag (t+1). Consumer
// thread polls ONE flag word (s_sleep backoff), then fetches ONE 64B line
// of its producer's data and verifies embedded tags (catches flag/data
// reordering). Own slice staged via LDS. No acquire/release, no drains.
// 2 lgkm-only barriers/step; h_s double-buffered by parity.
// ---------------------------------------------------------------------------
__global__ void __launch_bounds__(256) lstm_kernel(
    const float* __restrict__ Wgx, const float* __restrict__ Wix,
    const float* __restrict__ Wfx, const float* __restrict__ Wox,
    const float* __restrict__ Wgh, const float* __restrict__ Wih,
    const float* __restrict__ Wfh, const float* __restrict__ Woh,
    const float* __restrict__ bg,  const float* __restrict__ bi,
    const float* __restrict__ bf2, const float* __restrict__ bo,
    const uint32_t* __restrict__ xtf,
    uint64_t* __restrict__ hbuf,
    int* __restrict__ flags,
    const float* __restrict__ Wph, const float* __restrict__ bp,
    float* __restrict__ out)
{
    __shared__ __align__(16) unsigned short Wh_s[4][16][264];
    __shared__ __align__(16) unsigned short Wx_s[4][16][136];
    __shared__ __align__(16) unsigned short h_s[2][16][264];   // parity-buffered
    __shared__ float pre_s[4][16][17];
    __shared__ float bias_s[4][16];

    const int tid  = threadIdx.x;
    const int bc   = blockIdx.x & 15;
    const int hc   = blockIdx.x >> 4;
    const int wave = tid >> 6;
    const int lane = tid & 63;
    const int mrow = lane & 15;
    const int quad = lane >> 4;

    const float* Wh[4] = {Wgh, Wih, Wfh, Woh};
    const float* Wx[4] = {Wgx, Wix, Wfx, Wox};
    const float* bias[4] = {bg, bi, bf2, bo};

#pragma unroll
    for (int g = 0; g < 4; ++g) {
        for (int it = 0; it < 16; ++it) {
            int idx = it * 256 + tid;
            int k = idx >> 4, c = idx & 15;
            Wh_s[g][c][k] = f2bf(Wh[g][(size_t)k * H_ + hc * 16 + c]);
        }
        for (int it = 0; it < 8; ++it) {
            int idx = it * 256 + tid;
            int k = idx >> 4, c = idx & 15;
            Wx_s[g][c][k] = f2bf(Wx[g][(size_t)k * H_ + hc * 16 + c]);
        }
    }
    if (tid < 64) bias_s[tid >> 4][tid & 15] = bias[tid >> 4][hc * 16 + (tid & 15)];
    __syncthreads();

    const int b_l = tid >> 4;       // batch row within chunk (0..15)
    const int u_l = tid & 15;       // unit within slice (0..15)
    const int p_poll = b_l;         // producer this thread polls
    const int g_poll = u_l;         // row within producer's region
    const bool do_poll = (p_poll != hc);

    float c_st = 0.0f, h_st = 0.0f;

    // prefetch x fragments for t=0 (straight into MFMA A layout)
    uint4 xv[4];
#pragma unroll
    for (int kk = 0; kk < 4; ++kk)
        xv[kk] = *(const uint4*)(xtf + ((((size_t)0 * 16 + bc) * 4 + kk) * 64 + lane) * 4);

    for (int t = 0; t < T_; ++t) {
        // ---- x-projection MFMAs: register A-frags, no staging, no barrier ----
        f32x4 accx = {0.f, 0.f, 0.f, 0.f};
#pragma unroll
        for (int kk = 0; kk < 4; ++kk) {
            s16x8 a  = as_frag(xv[kk]);
            s16x8 bb = *(const s16x8*)&Wx_s[wave][mrow][kk * 32 + quad * 8];
            accx = __builtin_amdgcn_mfma_f32_16x16x32_bf16(a, bb, accx, 0, 0, 0);
        }

        // ---- detect + fetch h(t-1) ----
        if (t > 0 && do_poll) {
            while (__hip_atomic_load(&flags[bc * 16 + p_poll], __ATOMIC_RELAXED,
                                     __HIP_MEMORY_SCOPE_AGENT) < t) {
                __builtin_amdgcn_s_sleep(2);
            }
            const uint64_t* L = hbuf +
                ((((size_t)((t - 1) & 1) * 16 + bc) * 16 + p_poll) * 16 + g_poll) * 8;
            const uint32_t want = (uint32_t)(t - 1);
            uint64_t hv[8];
            while (true) {
#pragma unroll
                for (int i = 0; i < 8; ++i)
                    hv[i] = __hip_atomic_load(&L[i], __ATOMIC_RELAXED,
                                              __HIP_MEMORY_SCOPE_AGENT);
                bool ok = true;
#pragma unroll
                for (int i = 0; i < 8; ++i)
                    ok &= ((uint32_t)(hv[i] >> 32) == want);
                if (ok) break;
                __builtin_amdgcn_s_sleep(1);
            }
            uint32_t w[8];
#pragma unroll
            for (int i = 0; i < 8; ++i) w[i] = (uint32_t)hv[i];
            *(uint4*)&h_s[t & 1][g_poll][p_poll * 16]     = *(uint4*)&w[0];
            *(uint4*)&h_s[t & 1][g_poll][p_poll * 16 + 8] = *(uint4*)&w[4];
        }
        bar_lds();   // B1: h_s[t&1] fully staged (pollers + last step's local)

        // ---- h-projection MFMAs (2 independent chains) ----
        f32x4 acc0 = {0.f, 0.f, 0.f, 0.f};
        f32x4 acc1 = {0.f, 0.f, 0.f, 0.f};
        if (t > 0) {
#pragma unroll
            for (int j = 0; j < 4; ++j) {
                s16x8 a  = *(const s16x8*)&h_s[t & 1][mrow][(2 * j) * 32 + quad * 8];
                s16x8 bb = *(const s16x8*)&Wh_s[wave][mrow][(2 * j) * 32 + quad * 8];
                acc0 = __builtin_amdgcn_mfma_f32_16x16x32_bf16(a, bb, acc0, 0, 0, 0);
                s16x8 a2  = *(const s16x8*)&h_s[t & 1][mrow][(2 * j + 1) * 32 + quad * 8];
                s16x8 bb2 = *(const s16x8*)&Wh_s[wave][mrow][(2 * j + 1) * 32 + quad * 8];
                acc1 = __builtin_amdgcn_mfma_f32_16x16x32_bf16(a2, bb2, acc1, 0, 0, 0);
            }
        }

#pragma unroll
        for (int r = 0; r < 4; ++r)
            pre_s[wave][quad * 4 + r][mrow] = accx[r] + acc0[r] + acc1[r];
        bar_lds();   // B2: pre-activations ready

        float pg = pre_s[0][b_l][u_l] + bias_s[0][u_l];
        float pi = pre_s[1][b_l][u_l] + bias_s[1][u_l];
        float pf = pre_s[2][b_l][u_l] + bias_s[2][u_l];
        float po = pre_s[3][b_l][u_l] + bias_s[3][u_l];
        float gg = 2.0f * sigm(2.0f * pg) - 1.0f;   // tanh
        float ii = sigm(pi), ff = sigm(pf), oo = sigm(po);
        c_st = gg * ii + c_st * ff;
        float th = 2.0f * sigm(2.0f * c_st) - 1.0f; // tanh(c)
        h_st = th * oo;

        uint32_t hb = f2bf(h_st);

        // local staging of own slice for next step (no global round trip)
        h_s[(t + 1) & 1][b_l][hc * 16 + u_l] = (unsigned short)hb;

        // prefetch x fragments for t+1
        if (t + 1 < T_) {
#pragma unroll
            for (int kk = 0; kk < 4; ++kk)
                xv[kk] = *(const uint4*)(xtf +
                    ((((size_t)(t + 1) * 16 + bc) * 4 + kk) * 64 + lane) * 4);
        }

        // publish tagged data words, then flag (both relaxed; tags protect)
        uint32_t p32 = hb | ((uint32_t)__shfl_down((int)hb, 1, 64) << 16);
        if ((u_l & 1) == 0) {
            uint64_t val = (uint64_t)p32 | ((uint64_t)(uint32_t)t << 32);
            uint64_t* dst = hbuf +
                ((((size_t)(t & 1) * 16 + bc) * 16 + hc) * 16 + b_l) * 8 + (u_l >> 1);
            __hip_atomic_store(dst, val, __ATOMIC_RELAXED, __HIP_MEMORY_SCOPE_AGENT);
        }
        if (tid == 0)
            __hip_atomic_store(&flags[bc * 16 + hc], t + 1, __ATOMIC_RELAXED,
                               __HIP_MEMORY_SCOPE_AGENT);
    }

    // fused output projection
    {
        const int urow = hc * 16 + u_l;
        float wrow[C_];
#pragma unroll
        for (int c = 0; c < C_; ++c) wrow[c] = Wph[(size_t)urow * C_ + c];
#pragma unroll
        for (int c = 0; c < C_; ++c) {
            float v = h_st * wrow[c];
            v += __shfl_xor(v, 1, 64);
            v += __shfl_xor(v, 2, 64);
            v += __shfl_xor(v, 4, 64);
            v += __shfl_xor(v, 8, 64);
            if (u_l == 0) {
                if (hc == 0) v += bp[c];
                atomicAdd(&out[(size_t)(bc * 16 + b_l) * C_ + c], v);
            }
        }
    }
}

// ---------------------------------------------------------------------------
extern "C" void kernel_launch(void* const* d_in, const int* in_sizes, int n_in,
                              void* d_out, int out_size, void* d_ws, size_t ws_size,
                              hipStream_t stream) {
    const float* x   = (const float*)d_in[0];
    const float* Wgx = (const float*)d_in[1];
    const float* Wix = (const float*)d_in[2];
    const float* Wfx = (const float*)d_in[3];
    const float* Wox = (const float*)d_in[4];
    const float* Wgh = (const float*)d_in[5];
    const float* Wih = (const float*)d_in[6];
    const float* Wfh = (const float*)d_in[7];
    const float* Woh = (const float*)d_in[8];
    const float* bg  = (const float*)d_in[9];
    const float* bi  = (const float*)d_in[10];
    const float* bf2 = (const float*)d_in[11];
    const float* bo  = (const float*)d_in[12];
    const float* Wph = (const float*)d_in[13];
    const float* bp  = (const float*)d_in[14];

    char* ws = (char*)d_ws;
    // flags: 16 groups x 16 ints (64B line per group). Poison 0xAA = negative
    // int -> always < t under signed compare: no memset needed.
    int*      flags = (int*)ws;                         // 1 KiB reserved
    uint64_t* hbuf  = (uint64_t*)(ws + 1024);           // 512 KiB
    uint32_t* xtf   = (uint32_t*)(ws + 1024 + 2 * 16 * 16 * 16 * 8 * 8);

    hipMemsetAsync(d_out, 0, B_ * C_ * sizeof(float), stream);

    xt_kernel<<<16 * 32, 256, 0, stream>>>(x, xtf);

    lstm_kernel<<<256, 256, 0, stream>>>(Wgx, Wix, Wfx, Wox, Wgh, Wih, Wfh, Woh,
                                         bg, bi, bf2, bo, xtf, hbuf, flags,
                                         Wph, bp, (float*)d_out);
}